// Round 8
// baseline (130.761 us; speedup 1.0000x reference)
//
#include <hip/hip_runtime.h>
#include <hip/hip_bf16.h>
#include <math.h>

#define N_NODES 8192
#define DEG 32
#define EMBED 256
#define NHEAD 8
#define HDIM 32

typedef __attribute__((ext_vector_type(8))) short bf16x8;
typedef __attribute__((ext_vector_type(8))) unsigned short ushort8;
typedef __attribute__((ext_vector_type(4))) float f32x4;

__device__ __forceinline__ unsigned short f2bf(float x) {
    union { float f; unsigned int u; } c; c.f = x;
    unsigned int r = (c.u + 0x7FFFu + ((c.u >> 16) & 1u)) >> 16;
    return (unsigned short)r;
}
__device__ __forceinline__ float bf2f(unsigned short u) {
    union { unsigned int u; float f; } c; c.u = ((unsigned int)u) << 16;
    return c.f;
}

// C[M][N] = cvt_bf16(X) @ cvt_bf16(W)^T + bias  via MFMA 16x16x32 bf16.
// BM=BN=64, BK=64 (LDS 18.4 KB -> ~8 blocks/CU). 4 waves, each a 32x32
// quadrant (2x2 frags). Conversion f32->bf16 fused into LDS staging
// (bit-identical to the previous separate convert pass).
// IS_QKV=1: X=feats f32; W tile selected block-uniformly among Wq/Wk/Wv
//   (64-row tiles never span a 256-row boundary); cols<256 -> Qf f32,
//   cols>=256 -> KVb bf16 [8192][512] (K|V halves).
// IS_QKV=0: X=attb bf16; W=Wo f32; out f32.
template <int IS_QKV>
__global__ __launch_bounds__(256) void gemm_fused(
        const float* __restrict__ Xf,
        const unsigned short* __restrict__ Xb16,
        const float* __restrict__ W0, const float* __restrict__ W1,
        const float* __restrict__ W2,
        const float* __restrict__ b0, const float* __restrict__ b1,
        const float* __restrict__ b2,
        float* __restrict__ outF, unsigned short* __restrict__ outKV) {
    __shared__ unsigned short Xs[64][72];
    __shared__ unsigned short Ws[64][72];
    const int t    = threadIdx.x;
    const int bm   = blockIdx.y * 64;
    const int bn   = blockIdx.x * 64;        // global col base (0..767 / 0..255)
    const int lane = t & 63;
    const int wv   = t >> 6;
    const int wm   = (wv >> 1) * 32;
    const int wn   = (wv & 1) * 32;
    const int fr   = lane & 15;              // fragment row/col
    const int ksel = lane >> 4;              // 0..3 k-group

    const int seg = IS_QKV ? (int)(blockIdx.x >> 2) : 0;   // block-uniform
    const float* wsrc = (seg == 0) ? W0 : (seg == 1) ? W1 : W2;
    const float* bsrc = (seg == 0) ? b0 : (seg == 1) ? b1 : b2;
    const int wr0 = (IS_QKV ? (int)(blockIdx.x & 3) : (int)blockIdx.x) * 64;

    f32x4 acc[2][2] = {};

    for (int k0 = 0; k0 < 256; k0 += 64) {
        // --- stage X tile ---
        if (IS_QKV) {
#pragma unroll
            for (int i = 0; i < 4; ++i) {
                const int id  = i * 256 + t;     // 0..1023
                const int row = id >> 4;         // 0..63
                const int c4  = (id & 15) * 4;   // 0..60
                const float4 v = *reinterpret_cast<const float4*>(
                    &Xf[(bm + row) * 256 + k0 + c4]);
                ushort4 r;
                r.x = f2bf(v.x); r.y = f2bf(v.y); r.z = f2bf(v.z); r.w = f2bf(v.w);
                *reinterpret_cast<ushort4*>(&Xs[row][c4]) = r;
            }
        } else {
#pragma unroll
            for (int i = 0; i < 2; ++i) {
                const int id  = i * 256 + t;     // 0..511
                const int row = id >> 3;         // 0..63
                const int c   = (id & 7) * 8;    // 0..56
                *reinterpret_cast<uint4*>(&Xs[row][c]) =
                    *reinterpret_cast<const uint4*>(&Xb16[(bm + row) * 256 + k0 + c]);
            }
        }
        // --- stage W tile (f32 -> bf16) ---
#pragma unroll
        for (int i = 0; i < 4; ++i) {
            const int id  = i * 256 + t;
            const int row = id >> 4;
            const int c4  = (id & 15) * 4;
            const float4 v = *reinterpret_cast<const float4*>(
                &wsrc[(wr0 + row) * 256 + k0 + c4]);
            ushort4 r;
            r.x = f2bf(v.x); r.y = f2bf(v.y); r.z = f2bf(v.z); r.w = f2bf(v.w);
            *reinterpret_cast<ushort4*>(&Ws[row][c4]) = r;
        }
        __syncthreads();
#pragma unroll
        for (int kf = 0; kf < 2; ++kf) {
            const int ck = (kf * 4 + ksel) * 8;
            bf16x8 a0 = *reinterpret_cast<const bf16x8*>(&Xs[wm + fr][ck]);
            bf16x8 a1 = *reinterpret_cast<const bf16x8*>(&Xs[wm + 16 + fr][ck]);
            bf16x8 b0v = *reinterpret_cast<const bf16x8*>(&Ws[wn + fr][ck]);
            bf16x8 b1v = *reinterpret_cast<const bf16x8*>(&Ws[wn + 16 + fr][ck]);
            acc[0][0] = __builtin_amdgcn_mfma_f32_16x16x32_bf16(a0, b0v, acc[0][0], 0, 0, 0);
            acc[0][1] = __builtin_amdgcn_mfma_f32_16x16x32_bf16(a0, b1v, acc[0][1], 0, 0, 0);
            acc[1][0] = __builtin_amdgcn_mfma_f32_16x16x32_bf16(a1, b0v, acc[1][0], 0, 0, 0);
            acc[1][1] = __builtin_amdgcn_mfma_f32_16x16x32_bf16(a1, b1v, acc[1][1], 0, 0, 0);
        }
        __syncthreads();
    }

    // C/D frag: col = lane&15, row = (lane>>4)*4 + reg  [verified m89/m91]
#pragma unroll
    for (int mf = 0; mf < 2; ++mf)
#pragma unroll
        for (int nf = 0; nf < 2; ++nf)
#pragma unroll
            for (int reg = 0; reg < 4; ++reg) {
                const int row = bm + wm + mf * 16 + ksel * 4 + reg;
                const int col = bn + wn + nf * 16 + fr;          // global col
                const float v = acc[mf][nf][reg] + bsrc[col & 255];
                if (IS_QKV) {
                    if (col < 256) outF[row * 256 + col] = v;
                    else           outKV[row * 512 + (col - 256)] = f2bf(v);
                } else {
                    outF[row * 256 + col] = v;
                }
            }
}

// One block per dst node; 256 threads. ILP-restructured:
//  QK phase: thread (h,j) computes the FULL 32-dim dot in-thread from 4
//    independent 16B K gathers (no per-edge shuffle chains).
//  Softmax: one 5-shfl pass within 32-lane half-waves.
//  PV phase: thread (h,d): 32 independent coalesced gathers.
__global__ __launch_bounds__(256) void edge_attn(const float* __restrict__ Qf,
                                                 const unsigned short* __restrict__ KVb,
                                                 const int* __restrict__ edge_index,
                                                 unsigned short* __restrict__ attb) {
    const int n = blockIdx.x;
    const int t = threadIdx.x;
    const int h = t >> 5;     // head
    const int j = t & 31;     // edge slot (QK) / dim (PV)
    __shared__ int   s_src[DEG];
    __shared__ float Qs[EMBED];
    __shared__ float wls[NHEAD][DEG];

    if (t < DEG) s_src[t] = edge_index[(n * DEG + t) * 2];
    Qs[t] = Qf[n * EMBED + t];
    __syncthreads();

    // --- QK: dot(Q[h,:], K[src_j][h,:]) fully in-thread ---
    const unsigned short* kp = &KVb[(size_t)s_src[j] * 512 + h * HDIM];
    float s = 0.f;
#pragma unroll
    for (int c = 0; c < 4; ++c) {
        const ushort8 kv = *reinterpret_cast<const ushort8*>(&kp[c * 8]);
        const float4 q0 = *reinterpret_cast<const float4*>(&Qs[h * HDIM + c * 8]);
        const float4 q1 = *reinterpret_cast<const float4*>(&Qs[h * HDIM + c * 8 + 4]);
        s = fmaf(bf2f(kv[0]), q0.x, s);
        s = fmaf(bf2f(kv[1]), q0.y, s);
        s = fmaf(bf2f(kv[2]), q0.z, s);
        s = fmaf(bf2f(kv[3]), q0.w, s);
        s = fmaf(bf2f(kv[4]), q1.x, s);
        s = fmaf(bf2f(kv[5]), q1.y, s);
        s = fmaf(bf2f(kv[6]), q1.z, s);
        s = fmaf(bf2f(kv[7]), q1.w, s);
    }
    s *= 0.17677669529663687f;  // 1/sqrt(32)

    // --- softmax over the 32 edge slots ---
    float m = s;
    m = fmaxf(m, __shfl_xor(m, 1));
    m = fmaxf(m, __shfl_xor(m, 2));
    m = fmaxf(m, __shfl_xor(m, 4));
    m = fmaxf(m, __shfl_xor(m, 8));
    m = fmaxf(m, __shfl_xor(m, 16));
    const float p = __expf(s - m);
    float den = p;
    den += __shfl_xor(den, 1);
    den += __shfl_xor(den, 2);
    den += __shfl_xor(den, 4);
    den += __shfl_xor(den, 8);
    den += __shfl_xor(den, 16);
    wls[h][j] = p / den;
    __syncthreads();

    // --- PV: out[h,d] = sum_j w[h,j] * V[src_j][h,d] ---
    float o = 0.f;
#pragma unroll
    for (int jj = 0; jj < DEG; ++jj) {
        o = fmaf(wls[h][jj],
                 bf2f(KVb[(size_t)s_src[jj] * 512 + 256 + h * HDIM + j]), o);
    }
    attb[n * EMBED + t] = f2bf(o);
}

extern "C" void kernel_launch(void* const* d_in, const int* in_sizes, int n_in,
                              void* d_out, int out_size, void* d_ws, size_t ws_size,
                              hipStream_t stream) {
    const float* feats      = (const float*)d_in[0];
    const int*   edge_index = (const int*)d_in[1];
    const float* Wq = (const float*)d_in[3];
    const float* bq = (const float*)d_in[4];
    const float* Wk = (const float*)d_in[5];
    const float* bk = (const float*)d_in[6];
    const float* Wv = (const float*)d_in[7];
    const float* bv = (const float*)d_in[8];
    const float* Wo = (const float*)d_in[9];
    const float* bo = (const float*)d_in[10];
    float* out = (float*)d_out;

    // workspace layout (16B-aligned): Qf (8MB) | KVb (8MB) | attb (4MB)
    float*          Qf   = (float*)d_ws;
    unsigned short* KVb  = (unsigned short*)(Qf + (size_t)8192 * 256);
    unsigned short* attb = KVb + (size_t)8192 * 512;

    gemm_fused<1><<<dim3(12, 128), 256, 0, stream>>>(feats, nullptr,
                                                     Wq, Wk, Wv, bq, bk, bv,
                                                     Qf, KVb);
    edge_attn<<<N_NODES, 256, 0, stream>>>(Qf, KVb, edge_index, attb);
    gemm_fused<0><<<dim3(4, 128), 256, 0, stream>>>(nullptr, attb,
                                                    Wo, Wo, Wo, bo, bo, bo,
                                                    out, nullptr);
}